// Round 1
// baseline (93480.969 us; speedup 1.0000x reference)
//
#include <hip/hip_runtime.h>
#include <math.h>

// Problem constants (from reference)
#define Bsz   32
#define Lmem  512
#define Tsteps 400
#define EMBD  512
#define PRE   256
#define ENCD  512
#define ARNN  1024
#define DRNN  1024
#define NSYM  256
// MEAN_COEFF = 1.0f, SCALE_COEFF = 10.0f

// ---------------------------------------------------------------------------
// Prenet: xpre[t][b][:] = relu(pW2 @ relu(pW1 @ x + pb1) + pb2)
// x = zeros for t==0, else decoder_inputs[b,:,t-1]
// Grid: (T*B/8) blocks, 256 threads; 8 rows per block, thread = one neuron.
// ---------------------------------------------------------------------------
__global__ __launch_bounds__(256) void prenet_kernel(
    const float* __restrict__ din,   // (B, EMB, T)
    const float* __restrict__ pW1, const float* __restrict__ pb1,
    const float* __restrict__ pW2, const float* __restrict__ pb2,
    float* __restrict__ xpre)        // (T, B, PRE)
{
    __shared__ float xs[8][EMBD];
    __shared__ float h1s[8][PRE];
    const int tid = threadIdx.x;
    const int row0 = blockIdx.x * 8;

    // Stage the 8 input rows (strided global reads; one-time cost)
    for (int idx = tid; idx < 8 * EMBD; idx += 256) {
        int r = idx >> 9;
        int e = idx & 511;
        int rid = row0 + r;
        int t = rid >> 5;   // rows are t*32 + b
        int b = rid & 31;
        float v = 0.f;
        if (t > 0) v = din[(size_t)b * EMBD * Tsteps + (size_t)e * Tsteps + (t - 1)];
        xs[r][e] = v;
    }
    __syncthreads();

    // h1 = relu(x @ pW1.T + pb1), neuron = tid
    {
        float acc[8] = {0.f,0.f,0.f,0.f,0.f,0.f,0.f,0.f};
        const float* wr = pW1 + (size_t)tid * EMBD;
        for (int e = 0; e < EMBD; e += 4) {
            float4 wv = *(const float4*)(wr + e);
            #pragma unroll
            for (int r = 0; r < 8; ++r) {
                float4 xv = *(const float4*)&xs[r][e];
                acc[r] += wv.x * xv.x + wv.y * xv.y + wv.z * xv.z + wv.w * xv.w;
            }
        }
        float bias = pb1[tid];
        #pragma unroll
        for (int r = 0; r < 8; ++r) h1s[r][tid] = fmaxf(acc[r] + bias, 0.f);
    }
    __syncthreads();

    // h2 = relu(h1 @ pW2.T + pb2)
    {
        float acc[8] = {0.f,0.f,0.f,0.f,0.f,0.f,0.f,0.f};
        const float* wr = pW2 + (size_t)tid * PRE;
        for (int e = 0; e < PRE; e += 4) {
            float4 wv = *(const float4*)(wr + e);
            #pragma unroll
            for (int r = 0; r < 8; ++r) {
                float4 xv = *(const float4*)&h1s[r][e];
                acc[r] += wv.x * xv.x + wv.y * xv.y + wv.z * xv.z + wv.w * xv.w;
            }
        }
        float bias = pb2[tid];
        #pragma unroll
        for (int r = 0; r < 8; ++r) {
            int rid = row0 + r;
            int t = rid >> 5;
            int b = rid & 31;
            xpre[(size_t)t * Bsz * PRE + (size_t)b * PRE + tid] = fmaxf(acc[r] + bias, 0.f);
        }
    }
}

// ---------------------------------------------------------------------------
// Fused LSTM step kernel. One block = 8 units x 4 gates (32 W-rows) x all 32 b.
// Input = concat(segA[LA], segB[LB]) through Wih, segC[LC]=h_old through Whh.
// Thread tile: 2 rows x 2 batches. acts staged in LDS per 128-k chunk.
// h written to a separate buffer (double-buffered across steps); c in-place
// (block-owned elements only). Grid: HID/8 = 128 blocks, 256 threads.
// ---------------------------------------------------------------------------
template<int KIH, int KHH, int LA, int LB, int LC>
__global__ __launch_bounds__(256) void lstm_kernel(
    const float* __restrict__ Wih, const float* __restrict__ Whh,
    const float* __restrict__ bih, const float* __restrict__ bhh,
    const float* __restrict__ segA, const float* __restrict__ segB,
    const float* __restrict__ segC,
    float* __restrict__ c_state, float* __restrict__ h_out)
{
    __shared__ float acts[128][34];
    __shared__ float gbuf[32][33];
    const int tid = threadIdx.x;
    const int rg = tid >> 4;          // 0..15 -> rows 2rg, 2rg+1
    const int bg = (tid & 15) << 1;   // batch pair base (even)
    const int jl0 = rg << 1;
    const int jl1 = jl0 + 1;
    const int u0 = blockIdx.x << 3;
    const int j0 = (jl0 >> 3) * 1024 + u0 + (jl0 & 7);
    const int j1 = (jl1 >> 3) * 1024 + u0 + (jl1 & 7);
    const float* wih0 = Wih + (size_t)j0 * KIH;
    const float* wih1 = Wih + (size_t)j1 * KIH;
    const float* whh0 = Whh + (size_t)j0 * KHH;
    const float* whh1 = Whh + (size_t)j1 * KHH;

    float acc00 = 0.f, acc01 = 0.f, acc10 = 0.f, acc11 = 0.f;
    const int K = KIH + KHH;   // both multiples of 128; KIH % 128 == 0

    for (int kc = 0; kc < K; kc += 128) {
        __syncthreads();
        for (int idx = tid; idx < 32 * 128; idx += 256) {
            int b = idx >> 7;
            int kk = idx & 127;
            int k = kc + kk;
            float v;
            if (k < LA)           v = segA[b * LA + k];
            else if (k < LA + LB) v = segB[b * LB + (k - LA)];
            else                  v = segC[b * LC + (k - LA - LB)];
            acts[kk][b] = v;
        }
        __syncthreads();

        const float* w0base;
        const float* w1base;
        if (kc < KIH) { w0base = wih0 + kc; w1base = wih1 + kc; }
        else          { w0base = whh0 + (kc - KIH); w1base = whh1 + (kc - KIH); }

        #pragma unroll
        for (int kk = 0; kk < 128; kk += 4) {
            float4 w0 = *(const float4*)(w0base + kk);
            float4 w1 = *(const float4*)(w1base + kk);
            #pragma unroll
            for (int x = 0; x < 4; ++x) {
                float wa = (x == 0) ? w0.x : (x == 1) ? w0.y : (x == 2) ? w0.z : w0.w;
                float wb = (x == 0) ? w1.x : (x == 1) ? w1.y : (x == 2) ? w1.z : w1.w;
                float2 a = *(const float2*)&acts[kk + x][bg];
                acc00 = fmaf(wa, a.x, acc00);
                acc01 = fmaf(wa, a.y, acc01);
                acc10 = fmaf(wb, a.x, acc10);
                acc11 = fmaf(wb, a.y, acc11);
            }
        }
    }

    float bias0 = bih[j0] + bhh[j0];
    float bias1 = bih[j1] + bhh[j1];
    __syncthreads();
    gbuf[jl0][bg]     = acc00 + bias0;
    gbuf[jl0][bg + 1] = acc01 + bias0;
    gbuf[jl1][bg]     = acc10 + bias1;
    gbuf[jl1][bg + 1] = acc11 + bias1;
    __syncthreads();

    // LSTM cell update: thread = (b, unit)
    {
        int b = tid >> 3, ul = tid & 7;
        int u = u0 + ul;
        float gi = gbuf[ul][b];
        float gf = gbuf[8 + ul][b];
        float gg = gbuf[16 + ul][b];
        float go = gbuf[24 + ul][b];
        float co = c_state[b * 1024 + u];
        float si = 1.f / (1.f + expf(-gi));
        float sf = 1.f / (1.f + expf(-gf));
        float so = 1.f / (1.f + expf(-go));
        float cn = sf * co + si * tanhf(gg);
        float hn = so * tanhf(cn);
        c_state[b * 1024 + u] = cn;
        h_out[b * 1024 + u] = hn;
    }
}

// ---------------------------------------------------------------------------
// Fused attention: params = ah @ attWp.T + attbp (redundantly per block, bit-
// identical), mean update (double-buffered, dt==0 writes), Gaussian weights,
// ctx = w @ memory. Grid: 32 b x 8 d-tiles = 256 blocks, 256 threads.
// dt==0 block also writes aligns and ps outputs.
// ---------------------------------------------------------------------------
__global__ __launch_bounds__(256) void att_kernel(
    const float* __restrict__ ah,       // B x ARNN (new)
    const float* __restrict__ attWp,    // 2 x ARNN
    const float* __restrict__ attbp,    // 2
    const int*   __restrict__ mlen,     // B
    const float* __restrict__ memory,   // B x L x ENC
    const float* __restrict__ mean_in,  // B
    float* __restrict__ mean_out,       // B
    float* __restrict__ ctx,            // B x ENC
    float* __restrict__ aligns_out,     // (B,T,L)
    float* __restrict__ ps_out,         // (B,T,2)
    int t)
{
    const int b = blockIdx.x >> 3;
    const int dt = blockIdx.x & 7;
    const int tid = threadIdx.x;

    // params dot-products
    float p0 = 0.f, p1 = 0.f;
    for (int k = tid; k < ARNN; k += 256) {
        float a = ah[b * ARNN + k];
        p0 += a * attWp[k];
        p1 += a * attWp[ARNN + k];
    }
    #pragma unroll
    for (int off = 32; off > 0; off >>= 1) {
        p0 += __shfl_down(p0, off, 64);
        p1 += __shfl_down(p1, off, 64);
    }
    __shared__ float wred[4][2];
    __shared__ float bc[2];
    const int wid = tid >> 6;
    if ((tid & 63) == 0) { wred[wid][0] = p0; wred[wid][1] = p1; }
    __syncthreads();
    if (tid == 0) {
        float q0 = wred[0][0] + wred[1][0] + wred[2][0] + wred[3][0] + attbp[0];
        float q1 = wred[0][1] + wred[1][1] + wred[2][1] + wred[3][1] + attbp[1];
        float mn = mean_in[b] + expf(q0) * 1.0f;    // MEAN_COEFF
        float sc = expf(q1) * 10.0f;                // SCALE_COEFF
        if (dt == 0) {
            mean_out[b] = mn;
            ps_out[(size_t)b * Tsteps * 2 + (size_t)t * 2 + 0] = q0;
            ps_out[(size_t)b * Tsteps * 2 + (size_t)t * 2 + 1] = q1;
        }
        bc[0] = mn; bc[1] = sc;
    }
    __syncthreads();
    const float mn = bc[0], sc = bc[1];
    const float inv_s = 1.f / sc;
    const float coef = 0.3989422804014327f * inv_s;  // 1/sqrt(2*pi)/sc
    const int len = mlen[b];

    // Gaussian weights (shared), aligns written by dt==0 block
    __shared__ float wsh[Lmem];
    for (int l = tid; l < Lmem; l += 256) {
        float z = ((float)l - mn) * inv_s;
        float wv = (l < len) ? expf(-0.5f * z * z) * coef : 0.f;
        wsh[l] = wv;
        if (dt == 0)
            aligns_out[(size_t)b * Tsteps * Lmem + (size_t)t * Lmem + l] = wv;
    }
    __syncthreads();

    // ctx[b][d] = sum_l w[l] * memory[b][l][d], 4-way l-split per d
    const int d = (dt << 6) + (tid & 63);
    const int lq = tid >> 6;
    const float* mb = memory + (size_t)b * Lmem * ENCD + d;
    float acc = 0.f;
    for (int l = lq; l < len; l += 4)
        acc += wsh[l] * mb[(size_t)l * ENCD];

    __shared__ float red[4][64];
    red[lq][tid & 63] = acc;
    __syncthreads();
    if (tid < 64)
        ctx[b * ENCD + (dt << 6) + tid] =
            red[0][tid] + red[1][tid] + red[2][tid] + red[3][tid];
}

// ---------------------------------------------------------------------------
// Output projection: logits[b][t][:] += chunk of [dh,ctx] @ oW.T (+ ob on
// chunk 0), k-split over 8 chunks of 192 with atomicAdd (logits pre-zeroed).
// Grid: 32 n-groups x 8 k-chunks = 256 blocks, 256 threads.
// ---------------------------------------------------------------------------
__global__ __launch_bounds__(256) void out_kernel(
    const float* __restrict__ oW, const float* __restrict__ ob,
    const float* __restrict__ dh, const float* __restrict__ ctx,
    float* __restrict__ logits, int t)
{
    const int ng = blockIdx.x >> 3;
    const int kc = blockIdx.x & 7;
    const int tid = threadIdx.x;
    __shared__ float acts[192][33];
    const int k0 = kc * 192;
    for (int idx = tid; idx < 32 * 192; idx += 256) {
        int b = idx / 192;
        int kk = idx - b * 192;
        int k = k0 + kk;
        float v = (k < DRNN) ? dh[b * DRNN + k] : ctx[b * ENCD + (k - DRNN)];
        acts[kk][b] = v;
    }
    __syncthreads();
    const int nl = tid >> 5, b = tid & 31;
    const int n = ng * 8 + nl;
    const float* wr = oW + (size_t)n * (DRNN + ENCD) + k0;
    float acc = 0.f;
    #pragma unroll 8
    for (int kk = 0; kk < 192; kk += 4) {
        float4 wv = *(const float4*)(wr + kk);
        acc += wv.x * acts[kk][b] + wv.y * acts[kk + 1][b] +
               wv.z * acts[kk + 2][b] + wv.w * acts[kk + 3][b];
    }
    if (kc == 0) acc += ob[n];
    atomicAdd(&logits[(size_t)b * Tsteps * NSYM + (size_t)t * NSYM + n], acc);
}

// ---------------------------------------------------------------------------
extern "C" void kernel_launch(void* const* d_in, const int* in_sizes, int n_in,
                              void* d_out, int out_size, void* d_ws, size_t ws_size,
                              hipStream_t stream)
{
    (void)in_sizes; (void)n_in; (void)out_size; (void)ws_size;
    const float* memory = (const float*)d_in[0];
    const float* din    = (const float*)d_in[1];
    const int*   mlen   = (const int*)d_in[2];
    const float* pW1    = (const float*)d_in[3];
    const float* pb1    = (const float*)d_in[4];
    const float* pW2    = (const float*)d_in[5];
    const float* pb2    = (const float*)d_in[6];
    const float* aWih   = (const float*)d_in[7];
    const float* aWhh   = (const float*)d_in[8];
    const float* abih   = (const float*)d_in[9];
    const float* abhh   = (const float*)d_in[10];
    const float* attWp  = (const float*)d_in[11];
    const float* attbp  = (const float*)d_in[12];
    const float* dWih   = (const float*)d_in[13];
    const float* dWhh   = (const float*)d_in[14];
    const float* dbih   = (const float*)d_in[15];
    const float* dbhh   = (const float*)d_in[16];
    const float* oW     = (const float*)d_in[17];
    const float* ob     = (const float*)d_in[18];

    float* logits = (float*)d_out;                                  // B*T*NSYM
    float* aligns = logits + (size_t)Bsz * Tsteps * NSYM;           // B*T*L
    float* ps     = aligns + (size_t)Bsz * Tsteps * Lmem;           // B*T*2

    float* p = (float*)d_ws;
    float* xpre  = p; p += (size_t)Tsteps * Bsz * PRE;
    float* ah0   = p; p += Bsz * ARNN;
    float* ah1   = p; p += Bsz * ARNN;
    float* ac    = p; p += Bsz * ARNN;
    float* dh0   = p; p += Bsz * DRNN;
    float* dh1   = p; p += Bsz * DRNN;
    float* dc    = p; p += Bsz * DRNN;
    float* ctx   = p; p += Bsz * ENCD;
    float* mean0 = p; p += Bsz;
    float* mean1 = p; p += Bsz;

    // zero-init recurrent state (must happen every call; graph-capture safe)
    hipMemsetAsync(ah0,   0, Bsz * ARNN * sizeof(float), stream);
    hipMemsetAsync(ac,    0, Bsz * ARNN * sizeof(float), stream);
    hipMemsetAsync(dh0,   0, Bsz * DRNN * sizeof(float), stream);
    hipMemsetAsync(dc,    0, Bsz * DRNN * sizeof(float), stream);
    hipMemsetAsync(ctx,   0, Bsz * ENCD * sizeof(float), stream);
    hipMemsetAsync(mean0, 0, Bsz * sizeof(float), stream);
    hipMemsetAsync(logits, 0, (size_t)Bsz * Tsteps * NSYM * sizeof(float), stream);

    prenet_kernel<<<Tsteps * Bsz / 8, 256, 0, stream>>>(din, pW1, pb1, pW2, pb2, xpre);

    for (int t = 0; t < Tsteps; ++t) {
        float* ah_in  = (t & 1) ? ah1 : ah0;
        float* ah_out = (t & 1) ? ah0 : ah1;
        float* dh_in  = (t & 1) ? dh1 : dh0;
        float* dh_out = (t & 1) ? dh0 : dh1;
        float* mn_in  = (t & 1) ? mean1 : mean0;
        float* mn_out = (t & 1) ? mean0 : mean1;

        // attention LSTM: in = [xpre_t(256), ctx(512)] | hh = ah_in(1024)
        lstm_kernel<768, 1024, PRE, ENCD, ARNN><<<128, 256, 0, stream>>>(
            aWih, aWhh, abih, abhh,
            xpre + (size_t)t * Bsz * PRE, ctx, ah_in, ac, ah_out);

        att_kernel<<<256, 256, 0, stream>>>(
            ah_out, attWp, attbp, mlen, memory, mn_in, mn_out, ctx, aligns, ps, t);

        // decoder LSTM: in = [ah_out(1024), ctx(512)] | hh = dh_in(1024)
        lstm_kernel<1536, 1024, ARNN, ENCD, DRNN><<<128, 256, 0, stream>>>(
            dWih, dWhh, dbih, dbhh,
            ah_out, ctx, dh_in, dc, dh_out);

        out_kernel<<<256, 256, 0, stream>>>(oW, ob, dh_out, ctx, logits, t);
    }
}

// Round 2
// 17507.484 us; speedup vs baseline: 5.3395x; 5.3395x over previous
//
#include <hip/hip_runtime.h>
#include <math.h>

// Problem constants (from reference)
#define Bsz   32
#define Lmem  512
#define Tsteps 400
#define EMBD  512
#define PRE   256
#define ENCD  512
#define ARNN  1024
#define DRNN  1024
#define NSYM  256
// MEAN_COEFF = 1.0f, SCALE_COEFF = 10.0f

typedef _Float16 f16x8 __attribute__((ext_vector_type(8)));
typedef float    f32x4 __attribute__((ext_vector_type(4)));
typedef _Float16 half_t;

// ---------------------------------------------------------------------------
// Weight conversion/packing: Wcat[j][0..KIH-1] = Wih[j], [KIH..] = Whh[j], f16.
// bsum[j] = bih[j] + bhh[j]. Grid: 4096 blocks (one W-row each), 256 threads.
// ---------------------------------------------------------------------------
template<int KIH, int KHH>
__global__ __launch_bounds__(256) void conv_lstm_w(
    const float* __restrict__ Wih, const float* __restrict__ Whh,
    const float* __restrict__ bih, const float* __restrict__ bhh,
    half_t* __restrict__ Wcat, float* __restrict__ bsum)
{
    constexpr int K = KIH + KHH;
    const int j = blockIdx.x;
    const float* srcA = Wih + (size_t)j * KIH;
    const float* srcB = Whh + (size_t)j * KHH;
    half_t* dst = Wcat + (size_t)j * K;
    for (int k = threadIdx.x; k < KIH; k += 256) dst[k]       = (half_t)srcA[k];
    for (int k = threadIdx.x; k < KHH; k += 256) dst[KIH + k] = (half_t)srcB[k];
    if (threadIdx.x == 0) bsum[j] = bih[j] + bhh[j];
}

__global__ __launch_bounds__(256) void conv_mat(
    const float* __restrict__ src, half_t* __restrict__ dst, int n)
{
    for (int i = blockIdx.x * 256 + threadIdx.x; i < n; i += gridDim.x * 256)
        dst[i] = (half_t)src[i];
}

// ---------------------------------------------------------------------------
// Prenet: xpre[t][b][:] = relu(pW2 @ relu(pW1 @ x + pb1) + pb2)  (f16 output)
// ---------------------------------------------------------------------------
__global__ __launch_bounds__(256) void prenet_kernel(
    const float* __restrict__ din,   // (B, EMB, T)
    const float* __restrict__ pW1, const float* __restrict__ pb1,
    const float* __restrict__ pW2, const float* __restrict__ pb2,
    half_t* __restrict__ xpre)       // (T, B, PRE) f16
{
    __shared__ float xs[8][EMBD];
    __shared__ float h1s[8][PRE];
    const int tid = threadIdx.x;
    const int row0 = blockIdx.x * 8;

    for (int idx = tid; idx < 8 * EMBD; idx += 256) {
        int r = idx >> 9;
        int e = idx & 511;
        int rid = row0 + r;
        int t = rid >> 5;
        int b = rid & 31;
        float v = 0.f;
        if (t > 0) v = din[(size_t)b * EMBD * Tsteps + (size_t)e * Tsteps + (t - 1)];
        xs[r][e] = v;
    }
    __syncthreads();

    {
        float acc[8] = {0.f,0.f,0.f,0.f,0.f,0.f,0.f,0.f};
        const float* wr = pW1 + (size_t)tid * EMBD;
        for (int e = 0; e < EMBD; e += 4) {
            float4 wv = *(const float4*)(wr + e);
            #pragma unroll
            for (int r = 0; r < 8; ++r) {
                float4 xv = *(const float4*)&xs[r][e];
                acc[r] += wv.x * xv.x + wv.y * xv.y + wv.z * xv.z + wv.w * xv.w;
            }
        }
        float bias = pb1[tid];
        #pragma unroll
        for (int r = 0; r < 8; ++r) h1s[r][tid] = fmaxf(acc[r] + bias, 0.f);
    }
    __syncthreads();

    {
        float acc[8] = {0.f,0.f,0.f,0.f,0.f,0.f,0.f,0.f};
        const float* wr = pW2 + (size_t)tid * PRE;
        for (int e = 0; e < PRE; e += 4) {
            float4 wv = *(const float4*)(wr + e);
            #pragma unroll
            for (int r = 0; r < 8; ++r) {
                float4 xv = *(const float4*)&h1s[r][e];
                acc[r] += wv.x * xv.x + wv.y * xv.y + wv.z * xv.z + wv.w * xv.w;
            }
        }
        float bias = pb2[tid];
        #pragma unroll
        for (int r = 0; r < 8; ++r) {
            int rid = row0 + r;
            int t = rid >> 5;
            int b = rid & 31;
            xpre[(size_t)t * Bsz * PRE + (size_t)b * PRE + tid] =
                (half_t)fmaxf(acc[r] + bias, 0.f);
        }
    }
}

// ---------------------------------------------------------------------------
// MFMA LSTM step. G[4096][32] = Wcat[4096][K] @ actT[K][32] via
// mfma_f32_16x16x32_f16. Block = 4 units x 4 gates (16 rows) x 32 batches.
// 8 waves: btile = w&1 (batches 0-15 / 16-31), kq = w>>2..  w>>1 (K quarter).
// Acts read directly from global f16 segments (s0|s1|s2 concat along K).
// LDS: 4-way K-partial reduce + gate exchange; epilogue = fp32 cell update.
// A-frag: row m = lane&15 -> W-row j=(m>>2)*1024+u0+(m&3); k = 8*(lane>>4)+e.
// B-frag: col n = lane&15 -> batch;                        k = 8*(lane>>4)+e.
// D: col = lane&15 (batch), row = 4*(lane>>4)+reg  [guide m89 verified].
// Grid: 256 blocks x 512 threads (8 waves/CU on all 256 CUs).
// ---------------------------------------------------------------------------
template<int K, int L0, int L1, int L2>
__global__ __launch_bounds__(512) void lstm_mfma_kernel(
    const half_t* __restrict__ Wcat, const float* __restrict__ bsum,
    const half_t* __restrict__ s0, const half_t* __restrict__ s1,
    const half_t* __restrict__ s2,
    float* __restrict__ c_state, half_t* __restrict__ h_out)
{
    const int tid   = threadIdx.x;
    const int wave  = tid >> 6;
    const int lane  = tid & 63;
    const int btile = wave & 1;
    const int kq    = wave >> 1;
    const int u0    = blockIdx.x << 2;
    const int m15   = lane & 15;
    const int kh    = lane >> 4;
    constexpr int KQ = K / 4;
    const int kbase = kq * KQ;
    const int jrow  = (m15 >> 2) * 1024 + u0 + (m15 & 3);
    const int b     = (btile << 4) + m15;

    const half_t* arow = Wcat + (size_t)jrow * K + kbase + (kh << 3);
    f32x4 acc = {0.f, 0.f, 0.f, 0.f};

    #pragma unroll
    for (int ki = 0; ki < KQ; ki += 32) {
        f16x8 av = *(const f16x8*)(arow + ki);
        const int kg = kbase + ki + (kh << 3);
        const half_t* bp = (kg < L0)      ? (s0 + b * L0 + kg)
                         : (kg < L0 + L1) ? (s1 + b * L1 + (kg - L0))
                                          : (s2 + b * L2 + (kg - L0 - L1));
        f16x8 bv = *(const f16x8*)bp;
        acc = __builtin_amdgcn_mfma_f32_16x16x32_f16(av, bv, acc, 0, 0, 0);
    }

    __shared__ float gred[4][2][16][16];
    #pragma unroll
    for (int r = 0; r < 4; ++r)
        gred[kq][btile][(kh << 2) + r][m15] = acc[r];
    __syncthreads();

    if (tid < 128) {
        const int ul = tid >> 5;   // unit 0..3
        const int bb = tid & 31;   // batch
        const int bt = bb >> 4;
        const int n  = bb & 15;
        float g[4];
        #pragma unroll
        for (int gi = 0; gi < 4; ++gi) {
            const int mr = (gi << 2) + ul;
            g[gi] = gred[0][bt][mr][n] + gred[1][bt][mr][n]
                  + gred[2][bt][mr][n] + gred[3][bt][mr][n]
                  + bsum[gi * 1024 + u0 + ul];
        }
        const int idx = bb * 1024 + u0 + ul;
        float co = c_state[idx];
        float si = 1.f / (1.f + expf(-g[0]));
        float sf = 1.f / (1.f + expf(-g[1]));
        float so = 1.f / (1.f + expf(-g[3]));
        float cn = sf * co + si * tanhf(g[2]);
        float hn = so * tanhf(cn);
        c_state[idx] = cn;
        h_out[idx] = (half_t)hn;
    }
}

// ---------------------------------------------------------------------------
// Output projection via MFMA: logits[b][t][n] = [dh|ctx] @ Wo.T + ob.
// Same tiling as LSTM (16 rows x 32 b per block, 8 waves). Grid: 16 x 512.
// ---------------------------------------------------------------------------
__global__ __launch_bounds__(512) void out_mfma_kernel(
    const half_t* __restrict__ Wo, const float* __restrict__ ob,
    const half_t* __restrict__ dh, const half_t* __restrict__ ctx,
    float* __restrict__ logits, int t)
{
    const int tid   = threadIdx.x;
    const int wave  = tid >> 6;
    const int lane  = tid & 63;
    const int btile = wave & 1;
    const int kq    = wave >> 1;
    const int m15   = lane & 15;
    const int kh    = lane >> 4;
    constexpr int K  = DRNN + ENCD;   // 1536
    constexpr int KQ = K / 4;         // 384
    const int kbase = kq * KQ;
    const int n0 = blockIdx.x << 4;
    const int b  = (btile << 4) + m15;

    const half_t* arow = Wo + (size_t)(n0 + m15) * K + kbase + (kh << 3);
    f32x4 acc = {0.f, 0.f, 0.f, 0.f};

    #pragma unroll
    for (int ki = 0; ki < KQ; ki += 32) {
        f16x8 av = *(const f16x8*)(arow + ki);
        const int kg = kbase + ki + (kh << 3);
        const half_t* bp = (kg < DRNN) ? (dh + b * DRNN + kg)
                                       : (ctx + b * ENCD + (kg - DRNN));
        f16x8 bv = *(const f16x8*)bp;
        acc = __builtin_amdgcn_mfma_f32_16x16x32_f16(av, bv, acc, 0, 0, 0);
    }

    __shared__ float gred[4][2][16][16];
    #pragma unroll
    for (int r = 0; r < 4; ++r)
        gred[kq][btile][(kh << 2) + r][m15] = acc[r];
    __syncthreads();

    {
        const int m  = tid >> 5;   // 0..15
        const int bb = tid & 31;
        const int bt = bb >> 4;
        const int n  = bb & 15;
        float v = gred[0][bt][m][n] + gred[1][bt][m][n]
                + gred[2][bt][m][n] + gred[3][bt][m][n] + ob[n0 + m];
        logits[(size_t)bb * Tsteps * NSYM + (size_t)t * NSYM + n0 + m] = v;
    }
}

// ---------------------------------------------------------------------------
// Fused attention: params (redundant per block, bit-identical), mean update,
// Gaussian weights, ctx = w @ memory over the +-9 sigma window.
// Grid: 32 b x 8 d-tiles = 256 blocks, 256 threads.
// ---------------------------------------------------------------------------
__global__ __launch_bounds__(256) void att_kernel(
    const half_t* __restrict__ ah,      // B x ARNN (f16)
    const float* __restrict__ attWp,    // 2 x ARNN
    const float* __restrict__ attbp,    // 2
    const int*   __restrict__ mlen,     // B
    const float* __restrict__ memory,   // B x L x ENC (f32)
    const float* __restrict__ mean_in,  // B
    float* __restrict__ mean_out,       // B
    half_t* __restrict__ ctx,           // B x ENC (f16)
    float* __restrict__ aligns_out,     // (B,T,L)
    float* __restrict__ ps_out,         // (B,T,2)
    int t)
{
    const int b = blockIdx.x >> 3;
    const int dt = blockIdx.x & 7;
    const int tid = threadIdx.x;

    float p0 = 0.f, p1 = 0.f;
    for (int k = tid; k < ARNN; k += 256) {
        float a = (float)ah[b * ARNN + k];
        p0 += a * attWp[k];
        p1 += a * attWp[ARNN + k];
    }
    #pragma unroll
    for (int off = 32; off > 0; off >>= 1) {
        p0 += __shfl_down(p0, off, 64);
        p1 += __shfl_down(p1, off, 64);
    }
    __shared__ float wred[4][2];
    __shared__ float bc[2];
    const int wid = tid >> 6;
    if ((tid & 63) == 0) { wred[wid][0] = p0; wred[wid][1] = p1; }
    __syncthreads();
    if (tid == 0) {
        float q0 = wred[0][0] + wred[1][0] + wred[2][0] + wred[3][0] + attbp[0];
        float q1 = wred[0][1] + wred[1][1] + wred[2][1] + wred[3][1] + attbp[1];
        float mn = mean_in[b] + expf(q0) * 1.0f;    // MEAN_COEFF
        float sc = expf(q1) * 10.0f;                // SCALE_COEFF
        if (dt == 0) {
            mean_out[b] = mn;
            ps_out[(size_t)b * Tsteps * 2 + (size_t)t * 2 + 0] = q0;
            ps_out[(size_t)b * Tsteps * 2 + (size_t)t * 2 + 1] = q1;
        }
        bc[0] = mn; bc[1] = sc;
    }
    __syncthreads();
    const float mn = bc[0], sc = bc[1];
    const float inv_s = 1.f / sc;
    const float coef = 0.3989422804014327f * inv_s;
    const int len = mlen[b];

    __shared__ float wsh[Lmem];
    for (int l = tid; l < Lmem; l += 256) {
        float z = ((float)l - mn) * inv_s;
        float wv = (l < len) ? expf(-0.5f * z * z) * coef : 0.f;
        wsh[l] = wv;
        if (dt == 0)
            aligns_out[(size_t)b * Tsteps * Lmem + (size_t)t * Lmem + l] = wv;
    }
    __syncthreads();

    // ctx reduction restricted to +-9 sigma (w < 1e-19 outside)
    int lo = (int)fmaxf(0.f, floorf(mn - 9.f * sc));
    int hi = (int)fminf((float)len, ceilf(mn + 9.f * sc) + 1.f);

    const int d = (dt << 6) + (tid & 63);
    const int lq = tid >> 6;
    const float* mb = memory + (size_t)b * Lmem * ENCD + d;
    float acc = 0.f;
    for (int l = lo + lq; l < hi; l += 4)
        acc += wsh[l] * mb[(size_t)l * ENCD];

    __shared__ float red[4][64];
    red[lq][tid & 63] = acc;
    __syncthreads();
    if (tid < 64)
        ctx[b * ENCD + (dt << 6) + tid] =
            (half_t)(red[0][tid] + red[1][tid] + red[2][tid] + red[3][tid]);
}

// ---------------------------------------------------------------------------
extern "C" void kernel_launch(void* const* d_in, const int* in_sizes, int n_in,
                              void* d_out, int out_size, void* d_ws, size_t ws_size,
                              hipStream_t stream)
{
    (void)in_sizes; (void)n_in; (void)out_size; (void)ws_size;
    const float* memory = (const float*)d_in[0];
    const float* din    = (const float*)d_in[1];
    const int*   mlen   = (const int*)d_in[2];
    const float* pW1    = (const float*)d_in[3];
    const float* pb1    = (const float*)d_in[4];
    const float* pW2    = (const float*)d_in[5];
    const float* pb2    = (const float*)d_in[6];
    const float* aWih   = (const float*)d_in[7];
    const float* aWhh   = (const float*)d_in[8];
    const float* abih   = (const float*)d_in[9];
    const float* abhh   = (const float*)d_in[10];
    const float* attWp  = (const float*)d_in[11];
    const float* attbp  = (const float*)d_in[12];
    const float* dWih   = (const float*)d_in[13];
    const float* dWhh   = (const float*)d_in[14];
    const float* dbih   = (const float*)d_in[15];
    const float* dbhh   = (const float*)d_in[16];
    const float* oW     = (const float*)d_in[17];
    const float* ob     = (const float*)d_in[18];

    float* logits = (float*)d_out;                                  // B*T*NSYM
    float* aligns = logits + (size_t)Bsz * Tsteps * NSYM;           // B*T*L
    float* ps     = aligns + (size_t)Bsz * Tsteps * Lmem;           // B*T*2

    char* base = (char*)d_ws;
    auto alloc = [&](size_t bytes) -> char* {
        char* p = base; base += (bytes + 255) & ~(size_t)255; return p;
    };
    half_t* Wcat_a = (half_t*)alloc((size_t)4096 * 1792 * 2);
    half_t* Wcat_d = (half_t*)alloc((size_t)4096 * 2560 * 2);
    half_t* Wo     = (half_t*)alloc((size_t)NSYM * (DRNN + ENCD) * 2);
    float*  bsum_a = (float*)alloc(4096 * 4);
    float*  bsum_d = (float*)alloc(4096 * 4);
    half_t* xpre   = (half_t*)alloc((size_t)Tsteps * Bsz * PRE * 2);
    half_t* ah0    = (half_t*)alloc(Bsz * ARNN * 2);
    half_t* ah1    = (half_t*)alloc(Bsz * ARNN * 2);
    half_t* dh0    = (half_t*)alloc(Bsz * DRNN * 2);
    half_t* dh1    = (half_t*)alloc(Bsz * DRNN * 2);
    half_t* ctx    = (half_t*)alloc(Bsz * ENCD * 2);
    float*  ac     = (float*)alloc(Bsz * ARNN * 4);
    float*  dc     = (float*)alloc(Bsz * DRNN * 4);
    float*  mean0  = (float*)alloc(Bsz * 4);
    float*  mean1  = (float*)alloc(Bsz * 4);

    // zero-init recurrent state (every call; graph-capture safe)
    hipMemsetAsync(ah0,   0, Bsz * ARNN * 2, stream);
    hipMemsetAsync(dh0,   0, Bsz * DRNN * 2, stream);
    hipMemsetAsync(ctx,   0, Bsz * ENCD * 2, stream);
    hipMemsetAsync(ac,    0, Bsz * ARNN * 4, stream);
    hipMemsetAsync(dc,    0, Bsz * DRNN * 4, stream);
    hipMemsetAsync(mean0, 0, Bsz * 4, stream);

    // one-time weight conversion + prenet
    conv_lstm_w<PRE + ENCD, ARNN><<<4096, 256, 0, stream>>>(
        aWih, aWhh, abih, abhh, Wcat_a, bsum_a);
    conv_lstm_w<ARNN + ENCD, DRNN><<<4096, 256, 0, stream>>>(
        dWih, dWhh, dbih, dbhh, Wcat_d, bsum_d);
    conv_mat<<<768, 256, 0, stream>>>(oW, Wo, NSYM * (DRNN + ENCD));
    prenet_kernel<<<Tsteps * Bsz / 8, 256, 0, stream>>>(din, pW1, pb1, pW2, pb2, xpre);

    for (int t = 0; t < Tsteps; ++t) {
        half_t* ah_in  = (t & 1) ? ah1 : ah0;
        half_t* ah_out = (t & 1) ? ah0 : ah1;
        half_t* dh_in  = (t & 1) ? dh1 : dh0;
        half_t* dh_out = (t & 1) ? dh0 : dh1;
        float* mn_in  = (t & 1) ? mean1 : mean0;
        float* mn_out = (t & 1) ? mean0 : mean1;

        // attention LSTM: K = [xpre(256) | ctx(512) | ah_in(1024)] = 1792
        lstm_mfma_kernel<1792, PRE, ENCD, ARNN><<<256, 512, 0, stream>>>(
            Wcat_a, bsum_a, xpre + (size_t)t * Bsz * PRE, ctx, ah_in, ac, ah_out);

        att_kernel<<<256, 256, 0, stream>>>(
            ah_out, attWp, attbp, mlen, memory, mn_in, mn_out, ctx, aligns, ps, t);

        // decoder LSTM: K = [ah_out(1024) | ctx(512) | dh_in(1024)] = 2560
        lstm_mfma_kernel<2560, ARNN, ENCD, DRNN><<<256, 512, 0, stream>>>(
            Wcat_d, bsum_d, ah_out, ctx, dh_in, dc, dh_out);

        out_mfma_kernel<<<16, 512, 0, stream>>>(Wo, ob, dh_out, ctx, logits, t);
    }
}